// Round 13
// baseline (21.480 us; speedup 1.0000x reference)
//
#include <hip/hip_runtime.h>
#include <cstdint>

#define BTOT  4096
#define NBLK  1366   // 3 batches per wave; 5.34 blocks/CU (all co-resident at 26.6 KB)
#define T0    936    // simulate t in [936,1000): earlier steps are warmup (rounds 8/9)
#define NT    64
#define H1STR 68     // h1 row stride (dwords): %4==0 (b128 align), mod32=4 (bank spread)
#define LUTB  4080   // LUT base (dwords) = 60*H1STR
#define SMTOT 6640   // 4080 (h1) + 2560 (LUT); epilogue exchange reuses sm[0:64)

typedef float f32x4 __attribute__((ext_vector_type(4)));

// One wave per block. Main mapping: lanes 0..59 = 3 groups x 20 neurons.
// Phase-1 mapping: lanes 0..47 = 3 groups x 16 t-blocks (4 steps each); x read
// straight from global (coalesced). LUT[4][32][20] built VMEM-light from W2 with
// the 0.5 prescale folded in (bit-identical entries). Epilogue W3 reads are
// software-pipelined through named register tiles (wA/wB) so the 25-iteration
// q-loop exposes ~1 load latency instead of 25.
__global__ __launch_bounds__(64)
void snn_kernel(const float* __restrict__ x, const float* __restrict__ W1,
                const float* __restrict__ W2, const float* __restrict__ W3,
                float* __restrict__ out) {
  __shared__ __align__(16) float sm[SMTOT];
  float* lutf = sm + LUTB;
  const int lane = threadIdx.x;
  const int bid  = blockIdx.x;

  // ---- phase-1 x loads: issued FIRST, consumed after the LUT build ----
  const int pg = (lane >> 4) < 3 ? (lane >> 4) : 2;  // lanes 48..63 dup group 2
  const int tb = lane & 15;
  long bbp = (long)bid * 3 + pg;
  if (bbp > BTOT - 1) bbp = BTOT - 1;
  const float* xbase = x + bbp * 14000 + T0;
  f32x4 xl[14];
  #pragma unroll
  for (int l = 0; l < 14; ++l)
    xl[l] = *(const f32x4*)(xbase + l * 1000 + tb * 4);  // coalesced b128

  // ---- LUT build (lanes 0..39): lane (bi, half) owns neuron bi, q = 2*half+qr.
  // w2r prescaled by 0.5 (exact); ascending-k conditional adds -> entries
  // bit-identical to all prior rounds.
  if (lane < 40) {
    const int bi   = lane % 20;
    const int half = lane / 20;
    float w2r[10];
    const float* wsrc = W2 + bi * 20 + half * 10;
    #pragma unroll
    for (int k = 0; k < 5; ++k) {
      float2 t = *(const float2*)(wsrc + 2 * k);
      w2r[2 * k]     = 0.5f * t.x;
      w2r[2 * k + 1] = 0.5f * t.y;
    }
    float* dst = lutf + half * 1280 + bi;
    #pragma unroll
    for (int qr = 0; qr < 2; ++qr) {
      #pragma unroll
      for (int m = 0; m < 32; ++m) {
        float s = 0.f;
        if (m & 1)  s += w2r[qr * 5 + 0];
        if (m & 2)  s += w2r[qr * 5 + 1];
        if (m & 4)  s += w2r[qr * 5 + 2];
        if (m & 8)  s += w2r[qr * 5 + 3];
        if (m & 16) s += w2r[qr * 5 + 4];
        dst[qr * 640 + m * 20] = s;
      }
    }
  }

  // ---- phase-1: h1[g][i][t] = sum_l W1[i][l]*(0.5*x[g][l][t]) ----
  #pragma unroll
  for (int l = 0; l < 14; ++l) xl[l] = xl[l] * 0.5f;    // exact (exponent only)

  if (lane < 48) {
    float* hdst = sm + pg * 20 * H1STR + tb * 4;
    #pragma unroll
    for (int ii = 0; ii < 20; ++ii) {
      f32x4 acc = 0.f;
      #pragma unroll
      for (int l = 0; l < 14; ++l) {
        const float w = W1[ii * 14 + l];   // wave-uniform -> s_load
        const f32x4 wv = w;
        acc = __builtin_elementwise_fma(wv, xl[l], acc);  // v_pk_fma_f32
      }
      *(f32x4*)(hdst + ii * H1STR) = acc;
    }
  }

  const int  g3     = lane / 20;
  const int  g      = g3 < 3 ? g3 : 2;
  const int  i      = lane - g * 20;
  const int  i19    = i < 20 ? i : 19;
  const bool active = (g3 < 3);
  const long b      = (long)bid * 3 + g;
  const bool bvalid = (b < BTOT);

  float v1 = 0.f, v2 = 0.f, aacc = 0.f;
  const unsigned sh = 20u * (unsigned)g;

  __syncthreads();  // h1 + LUT visible

  const float* h1p = sm + (g * 20 + i19) * H1STR;

  #pragma unroll 8
  for (int tc4 = 0; tc4 < NT / 4; ++tc4) {
    const f32x4 h1v = *(const f32x4*)(h1p + tc4 * 4);  // one b128 per 4 steps

    // ---- Phase A: v1 chain + ballots ----
    unsigned mk[4];
    #pragma unroll
    for (int dt = 0; dt < 4; ++dt) {
      v1 = fmaf(v1, 0.5f, h1v[dt]);   // v' = v/2 + h/2 (h pre-scaled)
      const bool sp1 = (v1 >= 5.0f);
      v1 = sp1 ? 0.f : v1;
      mk[dt] = (unsigned)(__ballot(sp1) >> sh);  // bits >19 junk; bfe masks
    }

    // ---- Phase B: all 16 LUT loads issued back-to-back ----
    float hq[16];
    #pragma unroll
    for (int dt = 0; dt < 4; ++dt) {
      #pragma unroll
      for (int q = 0; q < 4; ++q)
        hq[dt * 4 + q] = lutf[q * 640 + ((mk[dt] >> (5 * q)) & 31u) * 20 + i19];
    }

    // ---- Phase C: v2 / aacc chain ----
    #pragma unroll
    for (int dt = 0; dt < 4; ++dt) {
      const float h2 = (hq[dt * 4 + 0] + hq[dt * 4 + 1]) +
                       (hq[dt * 4 + 2] + hq[dt * 4 + 3]);  // already *0.5
      v2 = fmaf(v2, 0.5f, h2);
      const bool sp2 = (v2 >= 5.0f);
      v2 = sp2 ? 0.f : v2;
      aacc = fmaf(aacc, 0.5f, sp2 ? 0.5f : 0.f);
    }
  }

  // ---- Epilogue: out[b][k] = exp( sum_j W3[k][j] * a[j] ), k = i + 20q ----
  // W3 tile q for this lane: 5 float4 at (const float4*)W3 + i19*5 + 100*q.
  // Pipelined: tiles q and q+1 live in named regs wA/wB; preloads issued before
  // the exchange barrier so their latency hides under it.
#define LOADW3(W, Q) {                                         \
    const float4* _p = (const float4*)W3 + i19 * 5 + 100 * (Q); \
    W##0 = _p[0]; W##1 = _p[1]; W##2 = _p[2];                   \
    W##3 = _p[3]; W##4 = _p[4]; }
#define DOTP(W, P)                                   \
    _a = fmaf(W##P.x, ar4[P].x, _a);                 \
    _a = fmaf(W##P.y, ar4[P].y, _a);                 \
    _a = fmaf(W##P.z, ar4[P].z, _a);                 \
    _a = fmaf(W##P.w, ar4[P].w, _a);
#define DOT5(W) ({ float _a = 0.f;                   \
    DOTP(W, 0) DOTP(W, 1) DOTP(W, 2) DOTP(W, 3) DOTP(W, 4) _a; })

  __syncthreads();
  if (active) sm[g * 20 + i] = aacc;   // exchange reuses h1 region (dead)
  float4 wA0, wA1, wA2, wA3, wA4, wB0, wB1, wB2, wB3, wB4;
  LOADW3(wA, 0)
  LOADW3(wB, 1)
  __syncthreads();
  if (active && bvalid) {
    float4 ar4[5];
    #pragma unroll
    for (int p = 0; p < 5; ++p)
      ar4[p] = *(const float4*)(sm + g * 20 + p * 4);
    float* ob = out + b * 500 + i;
    for (int q = 0; q < 24; q += 2) {
      const float accA = DOT5(wA);
      ob[20 * q] = __expf(accA);
      LOADW3(wA, q + 2)                 // q <= 22 -> tile <= 24, always valid
      const float accB = DOT5(wB);
      ob[20 * (q + 1)] = __expf(accB);
      if (q + 3 <= 24) LOADW3(wB, q + 3)
    }
    const float accT = DOT5(wA);        // tail tile 24
    ob[480] = __expf(accT);
  }
}

extern "C" void kernel_launch(void* const* d_in, const int* in_sizes, int n_in,
                              void* d_out, int out_size, void* d_ws, size_t ws_size,
                              hipStream_t stream) {
  const float* x  = (const float*)d_in[0];
  const float* W1 = (const float*)d_in[1];
  const float* W2 = (const float*)d_in[2];
  const float* W3 = (const float*)d_in[3];
  float* out = (float*)d_out;
  snn_kernel<<<dim3(NBLK), dim3(64), 0, stream>>>(x, W1, W2, W3, out);
}